// Round 3
// baseline (13510.902 us; speedup 1.0000x reference)
//
#include <hip/hip_runtime.h>

// ============================================================================
// 8-layer alternating-direction masked LSTM stack + embed + dense/softmax.
// R3: column-split LSTM. Grid = 8 blocks = 4 batch-groups x 2 h-col halves.
// Per block: Wh slab 256 KB fully register-resident (32 frags = 128 VGPR/wave).
// Cross-block h exchange per step via global hx + per-wave release flags
// (device-scope atomics; monotone values L*256+k+1; 2-slot ping-pong).
// xW repacked for 8B-coalesced loads; out/o-buffers in f16.
// ============================================================================

typedef _Float16 f16;
typedef _Float16 f16x8 __attribute__((ext_vector_type(8)));
typedef _Float16 f16x4 __attribute__((ext_vector_type(4)));
typedef float    f32x4 __attribute__((ext_vector_type(4)));

#define DEVI static __device__ __forceinline__

DEVI float fast_sigmoid(float x) {
  return __builtin_amdgcn_rcpf(1.f + __builtin_amdgcn_exp2f(-1.44269504f * x));
}
DEVI float fast_tanh(float x) {
  return 1.f - 2.f * __builtin_amdgcn_rcpf(1.f + __builtin_amdgcn_exp2f(2.88539008f * x));
}

// ---------------------------------------------------------------------------
// pack_frags: dst frag layout [L][kk][nt][lane][8 f16].
// B-frag (16x16x32): lane l holds B[k=kk*32+(l>>4)*8+e][col=nt*16+(l&15)]
// ---------------------------------------------------------------------------
__global__ void pack_frags(const float* __restrict__ src, f16* __restrict__ dst, int nct) {
  const int idx  = blockIdx.x * 256 + threadIdx.x;
  const int lane = idx & 63;
  const int f    = idx >> 6;
  const int nt   = f % nct;
  const int g2   = f / nct;
  const int kk   = g2 & 7;
  const int L    = g2 >> 3;
  const int ncols = nct * 16;
  const float* s = src + (size_t)(L * 256 + kk * 32 + (lane >> 4) * 8) * ncols + nt * 16 + (lane & 15);
  f16x8 v;
#pragma unroll
  for (int e = 0; e < 8; ++e) v[e] = (f16)s[(size_t)e * ncols];
  *(f16x8*)(dst + (size_t)idx * 8) = v;
}

// ---------------------------------------------------------------------------
__global__ void embed_k(const int* __restrict__ wid, const int* __restrict__ pid,
                        const float* __restrict__ emb1, const float* __restrict__ emb2,
                        f16* __restrict__ X) {
  const int r = blockIdx.x;
  const int d = threadIdx.x;                 // 0..127
  const int wv = wid[r], pv = pid[r];
  X[r * 256 + d]       = (f16)emb1[wv * 128 + d];
  X[r * 256 + 128 + d] = (f16)emb2[pv * 128 + d];
}

// ---------------------------------------------------------------------------
// make_input: X = a + b (f16, packed adds), 8 elems/thread
// ---------------------------------------------------------------------------
__global__ void make_input(const f16* __restrict__ a, const f16* __restrict__ b,
                           f16* __restrict__ X) {
  const size_t q = ((size_t)blockIdx.x * 256 + threadIdx.x) * 8;
  const f16x8 va = *(const f16x8*)(a + q);
  const f16x8 vb = *(const f16x8*)(b + q);
  *(f16x8*)(X + q) = va + vb;
}

// ---------------------------------------------------------------------------
// gemm_xw: xWp = pack(X[16384][256] @ Wi + bias)  (f16)
// packed store layout: xWp[row][ (cgd*8+t)*64 + r0*4 + q ]
//   where actual gate col = q*256 + cgd*128 + t*16 + r0
// ---------------------------------------------------------------------------
__global__ __launch_bounds__(512, 2) void gemm_xw(const f16* __restrict__ X,
                                                  const f16* __restrict__ wipf,
                                                  const float* __restrict__ bias,
                                                  f16* __restrict__ xWp) {
  extern __shared__ char smem[];  // 65536 B : A tile [128][256] f16, swizzled
  const int tid = threadIdx.x, lane = tid & 63, w = tid >> 6;
  const int nb = blockIdx.x, mb = blockIdx.y;
  const char* xbase = (const char*)X + (size_t)mb * 128 * 512;
#pragma unroll
  for (int i = 0; i < 8; ++i) {
    const int row = i * 16 + (tid >> 5);
    const int c16 = tid & 31;
    const uint4 v = *(const uint4*)(xbase + row * 512 + c16 * 16);
    *(uint4*)(smem + row * 512 + ((c16 ^ (row & 7)) << 4)) = v;
  }
  __syncthreads();

  const int mh = w >> 2, nw = w & 3;
  const char* wipf_c = (const char*)wipf;
  const float vb0 = bias[nb * 128 + nw * 32 + (lane & 15)];
  const float vb1 = bias[nb * 128 + nw * 32 + 16 + (lane & 15)];
  f32x4 acc[4][2] = {};
#pragma unroll
  for (int kk = 0; kk < 8; ++kk) {
    const f16x8 b0 = *(const f16x8*)(wipf_c + ((size_t)(kk * 64 + nb * 8 + nw * 2 + 0) << 10) + (lane << 4));
    const f16x8 b1 = *(const f16x8*)(wipf_c + ((size_t)(kk * 64 + nb * 8 + nw * 2 + 1) << 10) + (lane << 4));
#pragma unroll
    for (int m2 = 0; m2 < 4; ++m2) {
      const int row = mh * 64 + m2 * 16 + (lane & 15);
      const f16x8 a = *(const f16x8*)(smem + row * 512 + (((kk * 4 + (lane >> 4)) ^ (row & 7)) << 4));
      acc[m2][0] = __builtin_amdgcn_mfma_f32_16x16x32_f16(a, b0, acc[m2][0], 0, 0, 0);
      acc[m2][1] = __builtin_amdgcn_mfma_f32_16x16x32_f16(a, b1, acc[m2][1], 0, 0, 0);
    }
  }
#pragma unroll
  for (int m2 = 0; m2 < 4; ++m2)
#pragma unroll
    for (int n2 = 0; n2 < 2; ++n2)
#pragma unroll
      for (int j = 0; j < 4; ++j) {
        const int r   = mb * 128 + mh * 64 + m2 * 16 + (lane >> 4) * 4 + j;
        const int col = nb * 128 + nw * 32 + n2 * 16 + (lane & 15);
        const int q = col >> 8, rem = col & 255;
        const int cgd = rem >> 7, tt = (rem >> 4) & 7, r0c = rem & 15;
        xWp[(size_t)r * 1024 + (cgd * 8 + tt) * 64 + r0c * 4 + q] =
            (f16)(acc[m2][n2][j] + (n2 ? vb1 : vb0));
      }
}

// ---------------------------------------------------------------------------
// lstm_layer: 8 blocks = 4 batch-groups (16 rows) x 2 col-halves (128 h-cols).
// Wh fully register-resident per wave. h exchanged cross-block each step.
// ---------------------------------------------------------------------------
__global__ __launch_bounds__(512, 2) void lstm_layer(
    const f16*  __restrict__ xWp,   // packed [16384][1024] f16 (bias folded)
    const int*  __restrict__ wid,   // [64][256]
    const f16*  __restrict__ whp,   // layer frag slab: (kk*64+nt)*512 + lane*8
    f16* __restrict__ out,          // [64][256][256] f16
    f16* __restrict__ hx,           // [2 slots][8 parts][16][128] f16
    unsigned* __restrict__ flags,   // [8 parts][8 waves]
    int L, int reverse) {
  __shared__ f16 hbuf[2][16][264];               // double-buffered full h
  const int tid  = threadIdx.x;
  const int lane = tid & 63, w = tid >> 6;
  const int bg   = blockIdx.x >> 1, cg = blockIdx.x & 1;
  const int r0   = lane & 15, rg = lane >> 4;
  const int part = bg * 2 + cg, partp = bg * 2 + (cg ^ 1);
  const int hl   = w * 16 + r0;                  // own-half h col

  // persistent Wh fragments for this wave: 4 gates x 8 kk = 128 VGPR
  f16x8 regB[4][8];
#pragma unroll
  for (int q = 0; q < 4; ++q)
#pragma unroll
    for (int kk = 0; kk < 8; ++kk)
      regB[q][kk] = *(const f16x8*)(whp + (size_t)(kk * 64 + q * 16 + cg * 8 + w) * 512 + lane * 8);

  for (int i = tid; i < 2 * 16 * 264; i += 512) ((f16*)hbuf)[i] = (f16)0.f;

  float c[4] = {0.f, 0.f, 0.f, 0.f}, hreg[4] = {0.f, 0.f, 0.f, 0.f};

  __syncthreads();

#pragma unroll 1
  for (int k = 0; k < 256; ++k) {
    const int t_in = reverse ? (255 - k) : k;

    // 1) xW + mask loads (issued before poll -> latency hidden)
    f16x4 xwv[4];
    int widv[4];
#pragma unroll
    for (int j = 0; j < 4; ++j) {
      const int row = ((bg * 16 + rg * 4 + j) << 8) + t_in;
      widv[j] = wid[row];
      xwv[j] = *(const f16x4*)(xWp + (size_t)row * 1024 + (cg * 8 + w) * 64 + r0 * 4);
    }

    // 2) acquire partner half of H_k, copy into hbuf[k&1]
    if (k > 0) {
      const unsigned want = (unsigned)(L * 256 + k);
      if (lane < 8) {
        while (__hip_atomic_load(&flags[partp * 8 + lane], __ATOMIC_RELAXED,
                                 __HIP_MEMORY_SCOPE_AGENT) < want) {}
      }
      __builtin_amdgcn_fence(__ATOMIC_ACQUIRE, "agent");
      const f16* src = hx + ((size_t)(k & 1) * 8 + partp) * 2048;
      const int ii = tid * 4;                    // [0,2048)
      const int prow = ii >> 7, pcc = ii & 127;
      *(f16x4*)&hbuf[k & 1][prow][(cg ^ 1) * 128 + pcc] = *(const f16x4*)(src + ii);
      __builtin_amdgcn_sched_barrier(0);
      asm volatile("s_waitcnt lgkmcnt(0)\n\ts_barrier" ::: "memory");
      __builtin_amdgcn_sched_barrier(0);
    }

    // 3) z = H_k @ Wh(own cols): 32 MFMA, B all-register
    f32x4 acc[4] = {};
#pragma unroll
    for (int kk = 0; kk < 8; ++kk) {
      const f16x8 a = *(const f16x8*)&hbuf[k & 1][r0][kk * 32 + rg * 8];
#pragma unroll
      for (int q = 0; q < 4; ++q)
        acc[q] = __builtin_amdgcn_mfma_f32_16x16x32_f16(a, regB[q][kk], acc[q], 0, 0, 0);
    }

    // 4) gates + state (f32)
    f16 hv16[4];
#pragma unroll
    for (int j = 0; j < 4; ++j) {
      const float zi = acc[0][j] + (float)xwv[j][0];
      const float zf = acc[1][j] + (float)xwv[j][1];
      const float zc = acc[2][j] + (float)xwv[j][2];
      const float zo = acc[3][j] + (float)xwv[j][3];
      const float ig = fast_sigmoid(zi);
      const float fg = fast_sigmoid(zf);
      const float og = fast_sigmoid(zo);
      const float cb = fast_tanh(zc);
      const float cn = fg * c[j] + ig * cb;
      const float hn = og * fast_tanh(cn);
      const bool  m  = (widv[j] != 0);
      c[j]    = m ? cn : c[j];
      hreg[j] = m ? hn : hreg[j];
      hv16[j] = (f16)hreg[j];
    }

    // 5) publish H_{k+1}: LDS (own half), hx slot, per-wave release flag, out
    f16* hxw = hx + ((size_t)((k + 1) & 1) * 8 + part) * 2048;
#pragma unroll
    for (int j = 0; j < 4; ++j) {
      hbuf[(k + 1) & 1][rg * 4 + j][cg * 128 + hl] = hv16[j];
      hxw[(rg * 4 + j) * 128 + hl] = hv16[j];
    }
    if (lane == 0)
      __hip_atomic_store(&flags[part * 8 + w], (unsigned)(L * 256 + k + 1),
                         __ATOMIC_RELEASE, __HIP_MEMORY_SCOPE_AGENT);
#pragma unroll
    for (int j = 0; j < 4; ++j)
      out[((size_t)(bg * 16 + rg * 4 + j) * 256 + k) * 256 + cg * 128 + hl] = hv16[j];
  }
}

// ---------------------------------------------------------------------------
// final: softmax((o6+o7) @ Wd + bd) -> f32 out [16384][128]   (o* are f16)
// ---------------------------------------------------------------------------
__global__ __launch_bounds__(512, 2) void final_k(const f16* __restrict__ o0,
                                                  const f16* __restrict__ o1,
                                                  const f16* __restrict__ wdpf,
                                                  const float* __restrict__ bd,
                                                  float* __restrict__ outp) {
  const int tid = threadIdx.x, lane = tid & 63, w = tid >> 6;
  const int rbase = blockIdx.x * 128 + w * 16;
  const char* wdpf_c = (const char*)wdpf;

  f32x4 acc[8] = {};
#pragma unroll
  for (int kk = 0; kk < 8; ++kk) {
    const int r  = rbase + (lane & 15);
    const int k0 = kk * 32 + (lane >> 4) * 8;
    const f16x8 x = *(const f16x8*)(o0 + (size_t)r * 256 + k0);
    const f16x8 y = *(const f16x8*)(o1 + (size_t)r * 256 + k0);
    const f16x8 a = x + y;
#pragma unroll
    for (int nt = 0; nt < 8; ++nt) {
      const f16x8 b = *(const f16x8*)(wdpf_c + ((size_t)(kk * 8 + nt) << 10) + (lane << 4));
      acc[nt] = __builtin_amdgcn_mfma_f32_16x16x32_f16(a, b, acc[nt], 0, 0, 0);
    }
  }

  float vb[8];
#pragma unroll
  for (int nt = 0; nt < 8; ++nt) vb[nt] = bd[nt * 16 + (lane & 15)];

#pragma unroll
  for (int j = 0; j < 4; ++j) {
    float v[8];
#pragma unroll
    for (int nt = 0; nt < 8; ++nt) v[nt] = acc[nt][j] + vb[nt];
    float mx = v[0];
#pragma unroll
    for (int nt = 1; nt < 8; ++nt) mx = fmaxf(mx, v[nt]);
#pragma unroll
    for (int m = 1; m < 16; m <<= 1) mx = fmaxf(mx, __shfl_xor(mx, m, 64));
    float s = 0.f;
#pragma unroll
    for (int nt = 0; nt < 8; ++nt) {
      v[nt] = __builtin_amdgcn_exp2f(1.44269504f * (v[nt] - mx));
      s += v[nt];
    }
#pragma unroll
    for (int m = 1; m < 16; m <<= 1) s += __shfl_xor(s, m, 64);
    const float rs = __builtin_amdgcn_rcpf(s);
    const int r = rbase + (lane >> 4) * 4 + j;
#pragma unroll
    for (int nt = 0; nt < 8; ++nt)
      outp[(size_t)r * 128 + nt * 16 + (lane & 15)] = v[nt] * rs;
  }
}

// ---------------------------------------------------------------------------
extern "C" void kernel_launch(void* const* d_in, const int* in_sizes, int n_in,
                              void* d_out, int out_size, void* d_ws, size_t ws_size,
                              hipStream_t stream) {
  const int*   wid  = (const int*)d_in[0];
  const int*   pid  = (const int*)d_in[1];
  const float* emb1 = (const float*)d_in[2];
  const float* emb2 = (const float*)d_in[3];
  const float* Wis  = (const float*)d_in[4];
  const float* Whs  = (const float*)d_in[5];
  const float* bs   = (const float*)d_in[6];
  const float* Wd   = (const float*)d_in[7];
  const float* bd   = (const float*)d_in[8];

  char* ws = (char*)d_ws;
  f16*      Whp   = (f16*)(ws + 0);          //  4,194,304
  f16*      Wipf  = (f16*)(ws + 4194304);    //  4,194,304
  f16*      Wdpf  = (f16*)(ws + 8388608);    //     65,536
  f16*      X     = (f16*)(ws + 8454144);    //  8,388,608
  f16*      xWp   = (f16*)(ws + 16842752);   // 33,554,432
  f16*      o0    = (f16*)(ws + 50397184);   //  8,388,608
  f16*      o1    = (f16*)(ws + 58785792);   //  8,388,608
  f16*      hx    = (f16*)(ws + 67174400);   //     65,536
  unsigned* flags = (unsigned*)(ws + 67239936); //    256

  hipFuncSetAttribute((const void*)gemm_xw, hipFuncAttributeMaxDynamicSharedMemorySize, 65536);
  hipMemsetAsync(flags, 0, 256, stream);

  pack_frags<<<1024, 256, 0, stream>>>(Whs, Whp, 64);
  pack_frags<<<1024, 256, 0, stream>>>(Wis, Wipf, 64);
  pack_frags<<<16,   256, 0, stream>>>(Wd,  Wdpf, 8);
  embed_k<<<16384, 128, 0, stream>>>(wid, pid, emb1, emb2, X);

  f16* obuf[2] = {o0, o1};
  for (int L = 0; L < 8; ++L) {
    const f16* xin = X;
    if (L == 1) {
      xin = o0;                                   // identity input, same layout
    } else if (L >= 2) {
      make_input<<<2048, 256, 0, stream>>>(obuf[L & 1], obuf[(L - 1) & 1], X);
    }
    gemm_xw<<<dim3(8, 128), 512, 65536, stream>>>(xin, Wipf + (size_t)L * 262144,
                                                  bs + L * 1024, xWp);
    lstm_layer<<<8, 512, 0, stream>>>(xWp, wid, Whp + (size_t)L * 262144,
                                      obuf[L & 1], hx, flags, L, L & 1);
  }
  final_k<<<128, 512, 0, stream>>>(o0, o1, Wdpf, bd, (float*)d_out);
}